// Round 10
// baseline (443.169 us; speedup 1.0000x reference)
//
#include <hip/hip_runtime.h>
#include <hip/hip_bf16.h>

#define NPIX 4096
#define CCH  256
#define HID  64
#define BAT  4
#define XSTR 264    // proj LDS row stride (halfs)
#define PTS  136    // attn P-tile row stride (halfs): 16B-aligned rows

using f32x4 = __attribute__((ext_vector_type(4))) float;
using h16x8 = __attribute__((ext_vector_type(8))) _Float16;
using u16x4 = __attribute__((ext_vector_type(4))) unsigned short;

#define L2E 1.44269504088896340736f

__device__ __forceinline__ unsigned short f2h(float f) {
    _Float16 h = (_Float16)f;
    return __builtin_bit_cast(unsigned short, h);
}
__device__ __forceinline__ h16x8 ldg_fragh(const unsigned short* p) {
    uint4 v = *reinterpret_cast<const uint4*>(p);
    return __builtin_bit_cast(h16x8, v);
}
__device__ __forceinline__ h16x8 lds_fragh(const unsigned short* p) {
    return *reinterpret_cast<const h16x8*>(p);
}
__device__ __forceinline__ unsigned int pk2h(float a, float b) {
    auto t = __builtin_amdgcn_cvt_pkrtz(a, b);   // <2 x half>, RTZ
    return __builtin_bit_cast(unsigned int, t);
}
__device__ __forceinline__ float sel4(float a0, float a1, float a2, float a3, int q) {
    float x = (q & 1) ? a1 : a0;
    float y = (q & 1) ? a3 : a2;
    return (q & 2) ? y : x;
}

// ---------------------------------------------------------------------------
// W conversion -> row-major [384][256] fp16. Rows 0-63: Wq pre-scaled by
// log2(e) (softmax uses exp2), 64-127: Wk, 128-383: Wv.
// ---------------------------------------------------------------------------
__global__ __launch_bounds__(256, 1) void wcvt_kernel(
    const float* __restrict__ Wq, const float* __restrict__ Wk,
    const float* __restrict__ Wv, unsigned short* __restrict__ Wg)
{
    int idx = (blockIdx.x * 256 + threadIdx.x) * 4;
    int r = idx >> 8, c = idx & 255;
    const float* src = (r < 64)  ? (Wq + r * CCH + c)
                     : (r < 128) ? (Wk + (r - 64) * CCH + c)
                                 : (Wv + (r - 128) * CCH + c);
    float sc = (r < 64) ? L2E : 1.0f;
    float4 v4 = *reinterpret_cast<const float4*>(src);
    u16x4 hv;
    hv[0] = f2h(v4.x * sc); hv[1] = f2h(v4.y * sc);
    hv[2] = f2h(v4.z * sc); hv[3] = f2h(v4.w * sc);
    *reinterpret_cast<u16x4*>(Wg + idx) = hv;
}

// ---------------------------------------------------------------------------
// fp16 MFMA projection v9 (unchanged): operand order gives store-layout D.
// ---------------------------------------------------------------------------
__global__ __launch_bounds__(256, 2) void proj_kernel(
    const float* __restrict__ x1, const float* __restrict__ x2,
    const unsigned short* __restrict__ Wg,
    const float* __restrict__ bq, const float* __restrict__ bk,
    const float* __restrict__ bv,
    unsigned short* __restrict__ Qf, unsigned short* __restrict__ Kf,
    unsigned short* __restrict__ Vt)
{
    __shared__ unsigned short xs[32][XSTR];

    const int Lb = blockIdx.x;
    const int sb = Lb & 7;              // XCD-locality swizzle
    const int tile = Lb >> 3;
    const int s = sb >> 2, b = sb & 3;
    const float* x = s ? x2 : x1;
    const int n0 = tile * 32;
    const int t = threadIdx.x;
    const int lane = t & 63;
    const int w = __builtin_amdgcn_readfirstlane(t >> 6);
    const int quad = lane >> 4, lq = lane & 15;

    // stage x^T fp16 into LDS
    {
        const int n = t & 31;
        const int g = t >> 5;
        const float* xb = x + (size_t)(b * CCH) * NPIX + n0;
        #pragma unroll
        for (int i = 0; i < 8; ++i) {
            int c0 = g * 4 + i * 32;
            u16x4 hv;
            #pragma unroll
            for (int j = 0; j < 4; ++j)
                hv[j] = f2h(xb[(size_t)(c0 + j) * NPIX + n]);
            *reinterpret_cast<u16x4*>(&xs[n][c0]) = hv;
        }
    }
    __syncthreads();

    // hoist x fragments (both ntiles, full K=256)
    h16x8 xf[2][8];
    #pragma unroll
    for (int nt = 0; nt < 2; ++nt)
        #pragma unroll
        for (int ks = 0; ks < 8; ++ks)
            xf[nt][ks] = lds_fragh(&xs[nt * 16 + lq][ks * 32 + quad * 8]);

    const int sbN = (s * BAT + b) * NPIX;
    const int sbC = (s * BAT + b) * CCH;

    // W fragment double-buffer (hloop unrolled -> compile-time indices)
    h16x8 wf[2][8];
    {
        const unsigned short* wp = Wg + (size_t)((w * 6) * 16 + lq) * CCH + quad * 8;
        #pragma unroll
        for (int ks = 0; ks < 8; ++ks) wf[0][ks] = ldg_fragh(wp + ks * 32);
    }

    #pragma unroll
    for (int hloop = 0; hloop < 6; ++hloop) {
        const int cur = hloop & 1;
        const int idx = w * 6 + hloop;                  // wave-uniform, 0..23
        const int kind = idx < 4 ? 0 : (idx < 8 ? 1 : 2);

        if (hloop < 5) {
            const unsigned short* wp = Wg + (size_t)((idx + 1) * 16 + lq) * CCH + quad * 8;
            #pragma unroll
            for (int ks = 0; ks < 8; ++ks) wf[cur ^ 1][ks] = ldg_fragh(wp + ks * 32);
        }

        if (kind == 2) {
            const int cbase = (idx - 8) * 16;
            const float bbv = bv[cbase + lq];
            #pragma unroll
            for (int nt = 0; nt < 2; ++nt) {
                f32x4 acc = (f32x4){0.f, 0.f, 0.f, 0.f};
                #pragma unroll
                for (int ks = 0; ks < 8; ++ks)
                    acc = __builtin_amdgcn_mfma_f32_16x16x32_f16(xf[nt][ks], wf[cur][ks], acc, 0, 0, 0);
                u16x4 pk;
                #pragma unroll
                for (int reg = 0; reg < 4; ++reg) pk[reg] = f2h(acc[reg] + bbv);
                *reinterpret_cast<unsigned long long*>(
                    &Vt[(size_t)(sbC + cbase + lq) * NPIX + n0 + nt * 16 + quad * 4]) =
                    __builtin_bit_cast(unsigned long long, pk);
            }
        } else {
            unsigned short* dq = (kind ? Kf : Qf);
            const float* bias = (kind ? bk : bq);
            const float scl = kind ? 1.0f : L2E;
            const int hbase = (kind ? (idx - 4) : idx) * 16 + quad * 4;
            float bb4[4];
            #pragma unroll
            for (int reg = 0; reg < 4; ++reg) bb4[reg] = bias[hbase + reg] * scl;
            #pragma unroll
            for (int nt = 0; nt < 2; ++nt) {
                f32x4 acc = (f32x4){0.f, 0.f, 0.f, 0.f};
                #pragma unroll
                for (int ks = 0; ks < 8; ++ks)
                    acc = __builtin_amdgcn_mfma_f32_16x16x32_f16(wf[cur][ks], xf[nt][ks], acc, 0, 0, 0);
                u16x4 pk;
                #pragma unroll
                for (int reg = 0; reg < 4; ++reg) pk[reg] = f2h(acc[reg] + bb4[reg]);
                *reinterpret_cast<unsigned long long*>(
                    &dq[(size_t)(sbN + n0 + nt * 16 + lq) * HID + hbase]) =
                    __builtin_bit_cast(unsigned long long, pk);
            }
        }
    }
}

// ---------------------------------------------------------------------------
// Score-max kernel (v8-proven, unchanged).
// ---------------------------------------------------------------------------
__global__ __launch_bounds__(256, 2) void smax_kernel(
    const unsigned short* __restrict__ Qf, const unsigned short* __restrict__ Kf,
    float* __restrict__ Mg)
{
    __shared__ float Msh[4][64];

    const int Lb = blockIdx.x;
    const int g = Lb & 7;
    const int ntile = Lb >> 3;
    const int d = g >> 2, b = g & 3;
    const int db = d * BAT + b;
    const int s = d, r = 1 - d;
    const int n0 = ntile * 64;

    const int t = threadIdx.x;
    const int lane = t & 63;
    const int w = __builtin_amdgcn_readfirstlane(t >> 6);
    const int quad = lane >> 4, lq = lane & 15;

    const unsigned short* Qb = Qf + (size_t)(s * BAT + b) * NPIX * HID;
    const unsigned short* Kb = Kf + (size_t)(r * BAT + b) * NPIX * HID;

    h16x8 qf[4][2];
    #pragma unroll
    for (int nt = 0; nt < 4; ++nt)
        #pragma unroll
        for (int ks = 0; ks < 2; ++ks)
            qf[nt][ks] = ldg_fragh(Qb + (n0 + nt * 16 + lq) * HID + ks * 32 + quad * 8);

    float mx[4] = {-3.0e38f, -3.0e38f, -3.0e38f, -3.0e38f};

    h16x8 kfA[2][2], kfB[2][2];

#define SMAX_LOAD(BUF, IT)                                                      \
    {                                                                           \
        _Pragma("unroll")                                                       \
        for (int mt = 0; mt < 2; ++mt) {                                        \
            _Pragma("unroll")                                                   \
            for (int ks = 0; ks < 2; ++ks)                                      \
                BUF[mt][ks] = ldg_fragh(                                        \
                    Kb + ((IT) * 128 + w * 32 + mt * 16 + lq) * HID             \
                       + ks * 32 + quad * 8);                                   \
        }                                                                       \
    }
#define SMAX_STEP(BUF)                                                          \
    {                                                                           \
        f32x4 Sacc[2][4];                                                       \
        _Pragma("unroll")                                                       \
        for (int mt = 0; mt < 2; ++mt) {                                        \
            _Pragma("unroll")                                                   \
            for (int nt = 0; nt < 4; ++nt)                                      \
                Sacc[mt][nt] = (f32x4){0.f, 0.f, 0.f, 0.f};                     \
        }                                                                       \
        _Pragma("unroll")                                                       \
        for (int mt = 0; mt < 2; ++mt) {                                        \
            _Pragma("unroll")                                                   \
            for (int ks = 0; ks < 2; ++ks) {                                    \
                _Pragma("unroll")                                               \
                for (int nt = 0; nt < 4; ++nt)                                  \
                    Sacc[mt][nt] = __builtin_amdgcn_mfma_f32_16x16x32_f16(      \
                        BUF[mt][ks], qf[nt][ks], Sacc[mt][nt], 0, 0, 0);        \
            }                                                                   \
        }                                                                       \
        _Pragma("unroll")                                                       \
        for (int mt = 0; mt < 2; ++mt) {                                        \
            _Pragma("unroll")                                                   \
            for (int nt = 0; nt < 4; ++nt)                                      \
                mx[nt] = fmaxf(mx[nt],                                          \
                    fmaxf(fmaxf(Sacc[mt][nt][0], Sacc[mt][nt][1]),              \
                          fmaxf(Sacc[mt][nt][2], Sacc[mt][nt][3])));            \
        }                                                                       \
    }

    SMAX_LOAD(kfA, 0)
    for (int it = 0; it < 32; it += 2) {
        if (it + 1 < 32) SMAX_LOAD(kfB, it + 1)
        SMAX_STEP(kfA)
        if (it + 2 < 32) SMAX_LOAD(kfA, it + 2)
        SMAX_STEP(kfB)
    }
#undef SMAX_LOAD
#undef SMAX_STEP

    #pragma unroll
    for (int nt = 0; nt < 4; ++nt) {
        mx[nt] = fmaxf(mx[nt], __shfl_xor(mx[nt], 16));
        mx[nt] = fmaxf(mx[nt], __shfl_xor(mx[nt], 32));
    }
    Msh[w][quad * 16 + lq] = sel4(mx[0], mx[1], mx[2], mx[3], quad);
    __syncthreads();

    if (t < 64) {
        float m = fmaxf(fmaxf(Msh[0][t], Msh[1][t]), fmaxf(Msh[2][t], Msh[3][t]));
        Mg[(size_t)db * NPIX + n0 + t] = m;
    }
}

// ---------------------------------------------------------------------------
// Flash cross-attention v10: OCCUPANCY-FIRST. Grid 1024 (32 q-rows/block,
// no duplicated work), __launch_bounds__(256,4) -> 4 blocks/CU = 16 waves/CU
// (vs 8 before). All manual prefetching removed (rounds 5-9 proved it
// worthless at low occupancy); per-wave stalls are hidden by TLP.
// Per 128-m iter: S (8 MFMA/wave) -> exp2 (16/lane) -> P fp16 to dbuf LDS ->
// one barrier -> PV (32 MFMA/wave, V streamed from L2).
// ---------------------------------------------------------------------------
__global__ __launch_bounds__(256, 4) void attn_kernel(
    const float* __restrict__ x1, const float* __restrict__ x2,
    const unsigned short* __restrict__ Qf, const unsigned short* __restrict__ Kf,
    const unsigned short* __restrict__ Vt,
    const float* __restrict__ Mg, const float* __restrict__ gamma,
    float* __restrict__ out)
{
    __shared__ unsigned short PT[2][32 * PTS];   // P^T [n=32][m=128], fp16, dbuf
    __shared__ float Lsh[4][32];

    const int Lb = blockIdx.x;
    const int g = Lb & 7;                        // XCD-locality swizzle
    const int tile = Lb >> 3;                    // 0..127
    const int d = g >> 2, b = g & 3;
    const int db = d * BAT + b;
    const int s = d, r = 1 - d;
    const int n0 = tile * 32;

    const int t = threadIdx.x;
    const int lane = t & 63;
    const int w = __builtin_amdgcn_readfirstlane(t >> 6);
    const int quad = lane >> 4, lq = lane & 15;

    const unsigned short* Qb = Qf + (size_t)(s * BAT + b) * NPIX * HID;
    const unsigned short* Kb = Kf + (size_t)(r * BAT + b) * NPIX * HID;
    const unsigned short* Vb = Vt + (size_t)(r * BAT + b) * CCH * NPIX;

    // per-column max (exp2 units) from smax_kernel; columns n0 + nt*16 + lq
    float Mn[2];
    #pragma unroll
    for (int nt = 0; nt < 2; ++nt)
        Mn[nt] = Mg[(size_t)db * NPIX + n0 + nt * 16 + lq];

    // Q fragments, persistent (B-frags), 16 regs
    h16x8 qf[2][2];
    #pragma unroll
    for (int nt = 0; nt < 2; ++nt)
        #pragma unroll
        for (int ks = 0; ks < 2; ++ks)
            qf[nt][ks] = ldg_fragh(Qb + (n0 + nt * 16 + lq) * HID + ks * 32 + quad * 8);

    f32x4 Oacc[4][2];   // [rt][ct] : c = w*64+rt*16+..., n = n0+ct*16+lq
    #pragma unroll
    for (int rt = 0; rt < 4; ++rt)
        #pragma unroll
        for (int ct = 0; ct < 2; ++ct)
            Oacc[rt][ct] = (f32x4){0.f, 0.f, 0.f, 0.f};

    float Li[2] = {0.f, 0.f};

    for (int it = 0; it < 32; ++it) {
        const int buf = it & 1;
        const int m0 = it * 128;

        // ---- S phase: wave's 32 m-rows x 32 n; K loaded here (no prefetch) ----
        h16x8 kf[2][2];
        #pragma unroll
        for (int mt = 0; mt < 2; ++mt)
            #pragma unroll
            for (int ks = 0; ks < 2; ++ks)
                kf[mt][ks] = ldg_fragh(Kb + (m0 + w * 32 + mt * 16 + lq) * HID
                                          + ks * 32 + quad * 8);

        f32x4 Sacc[2][2];
        #pragma unroll
        for (int mt = 0; mt < 2; ++mt)
            #pragma unroll
            for (int nt = 0; nt < 2; ++nt)
                Sacc[mt][nt] = (f32x4){-Mn[nt], -Mn[nt], -Mn[nt], -Mn[nt]};
        #pragma unroll
        for (int mt = 0; mt < 2; ++mt)
            #pragma unroll
            for (int ks = 0; ks < 2; ++ks)
                #pragma unroll
                for (int nt = 0; nt < 2; ++nt)
                    Sacc[mt][nt] = __builtin_amdgcn_mfma_f32_16x16x32_f16(
                        kf[mt][ks], qf[nt][ks], Sacc[mt][nt], 0, 0, 0);

        // ---- softmax: P = exp2(S - M) <= 1, fp16, straight to LDS ----
        #pragma unroll
        for (int mt = 0; mt < 2; ++mt)
            #pragma unroll
            for (int nt = 0; nt < 2; ++nt) {
                float p0 = __builtin_amdgcn_exp2f(Sacc[mt][nt][0]);
                float p1 = __builtin_amdgcn_exp2f(Sacc[mt][nt][1]);
                float p2 = __builtin_amdgcn_exp2f(Sacc[mt][nt][2]);
                float p3 = __builtin_amdgcn_exp2f(Sacc[mt][nt][3]);
                Li[nt] += (p0 + p1) + (p2 + p3);
                uint2 pk2;
                pk2.x = pk2h(p0, p1);
                pk2.y = pk2h(p2, p3);
                *reinterpret_cast<uint2*>(
                    &PT[buf][(nt * 16 + lq) * PTS + w * 32 + mt * 16 + quad * 4]) = pk2;
            }
        __syncthreads();   // one barrier: P(it) visible

        // ---- PV: wave's 64 c-rows x 32 n over 128 m; V streamed ----
        #pragma unroll
        for (int ks = 0; ks < 4; ++ks) {
            h16x8 vf[4];
            #pragma unroll
            for (int rt = 0; rt < 4; ++rt)
                vf[rt] = ldg_fragh(Vb + (size_t)(w * 64 + rt * 16 + lq) * NPIX
                                      + m0 + ks * 32 + quad * 8);
            h16x8 pf[2];
            #pragma unroll
            for (int ct = 0; ct < 2; ++ct)
                pf[ct] = lds_fragh(&PT[buf][(ct * 16 + lq) * PTS + ks * 32 + quad * 8]);
            #pragma unroll
            for (int rt = 0; rt < 4; ++rt)
                #pragma unroll
                for (int ct = 0; ct < 2; ++ct)
                    Oacc[rt][ct] = __builtin_amdgcn_mfma_f32_16x16x32_f16(
                        vf[rt], pf[ct], Oacc[rt][ct], 0, 0, 0);
        }
    }

    // ---- epilogue: merge per-wave L across quads/waves, write out ----
    #pragma unroll
    for (int nt = 0; nt < 2; ++nt) {
        Li[nt] += __shfl_xor(Li[nt], 16);
        Li[nt] += __shfl_xor(Li[nt], 32);
    }
    if (quad == 0) {
        Lsh[w][lq] = Li[0];
        Lsh[w][16 + lq] = Li[1];
    }
    __syncthreads();

    float inv[2];
    #pragma unroll
    for (int nt = 0; nt < 2; ++nt) {
        int i = nt * 16 + lq;
        inv[nt] = 1.0f / ((Lsh[0][i] + Lsh[1][i]) + (Lsh[2][i] + Lsh[3][i]));
    }

    const float* xq = d ? x2 : x1;
    const float gm = gamma[0];

    #pragma unroll
    for (int rt = 0; rt < 4; ++rt)
        #pragma unroll
        for (int ct = 0; ct < 2; ++ct)
            #pragma unroll
            for (int rg = 0; rg < 4; ++rg) {
                int c = w * 64 + rt * 16 + quad * 4 + rg;
                int nn = n0 + ct * 16 + lq;
                size_t src = (size_t)(b * CCH + c) * NPIX + nn;
                size_t dst = (size_t)(db * CCH + c) * NPIX + nn;
                out[dst] = xq[src] + gm * Oacc[rt][ct][rg] * inv[ct];
            }
}

// ---------------------------------------------------------------------------
extern "C" void kernel_launch(void* const* d_in, const int* in_sizes, int n_in,
                              void* d_out, int out_size, void* d_ws, size_t ws_size,
                              hipStream_t stream) {
    (void)in_sizes; (void)n_in; (void)out_size; (void)ws_size;
    const float* x1 = (const float*)d_in[0];
    const float* x2 = (const float*)d_in[1];
    const float* Wq = (const float*)d_in[2];
    const float* bq = (const float*)d_in[3];
    const float* Wk = (const float*)d_in[4];
    const float* bk = (const float*)d_in[5];
    const float* Wv = (const float*)d_in[6];
    const float* bv = (const float*)d_in[7];
    const float* gm = (const float*)d_in[8];
    float* out = (float*)d_out;

    // ws (u16 elems): Qf 2.1M | Kf 2.1M | Vt 8.4M | Wg 98304, then Mg fp32 32768
    unsigned short* ws = (unsigned short*)d_ws;
    unsigned short* Qf = ws;
    unsigned short* Kf = Qf + (size_t)2097152;
    unsigned short* Vt = Kf + (size_t)2097152;
    unsigned short* Wg = Vt + (size_t)8388608;
    float* Mg = (float*)(Wg + 98304);

    wcvt_kernel<<<dim3(96), dim3(256), 0, stream>>>(Wq, Wk, Wv, Wg);
    proj_kernel<<<dim3(1024), dim3(256), 0, stream>>>(
        x1, x2, Wg, bq, bk, bv, Qf, Kf, Vt);
    smax_kernel<<<dim3(512), dim3(256), 0, stream>>>(Qf, Kf, Mg);
    attn_kernel<<<dim3(1024), dim3(256), 0, stream>>>(
        x1, x2, Qf, Kf, Vt, Mg, gm, out);
}

// Round 11
// 208.415 us; speedup vs baseline: 2.1264x; 2.1264x over previous
//
#include <hip/hip_runtime.h>
#include <hip/hip_bf16.h>

#define NPIX 4096
#define CCH  256
#define HID  64
#define BAT  4
#define XSTR 264    // proj LDS row stride (halfs)
#define PTS  136    // attn P-tile row stride (halfs)

// Fragment-order tensor layout (the round-11 change):
//   All MFMA operand tensors (Qf, Kf, Vt, Wg) are stored as 16x32 fragment
//   tiles of 512 halfs (1 KB), arranged so a wave's fragment load is
//   base + lane*8 halfs -> ONE contiguous 1KB segment per instruction.
//   (v10 post-mortem: per-lane 16B gathers spanning 16 strided rows = 16
//   scattered 64B segments per load -> TA/L1 segment-throughput bound.)
//   Element (row r, k) of a tile lives at halfs offset
//     (((k%32)>>3)*16 + (r%16))*8 + (k%8)      [r = m/c/n-row, k = h or m]
//   which matches both A- and B-operand lane maps (lane = (k_octet)*16 + r).

using f32x4 = __attribute__((ext_vector_type(4))) float;
using h16x8 = __attribute__((ext_vector_type(8))) _Float16;
using u16x4 = __attribute__((ext_vector_type(4))) unsigned short;

#define L2E 1.44269504088896340736f

__device__ __forceinline__ unsigned short f2h(float f) {
    _Float16 h = (_Float16)f;
    return __builtin_bit_cast(unsigned short, h);
}
__device__ __forceinline__ h16x8 ldg_fragh(const unsigned short* p) {
    uint4 v = *reinterpret_cast<const uint4*>(p);
    return __builtin_bit_cast(h16x8, v);
}
__device__ __forceinline__ h16x8 lds_fragh(const unsigned short* p) {
    return *reinterpret_cast<const h16x8*>(p);
}
__device__ __forceinline__ unsigned int pk2h(float a, float b) {
    auto t = __builtin_amdgcn_cvt_pkrtz(a, b);   // <2 x half>, RTZ
    return __builtin_bit_cast(unsigned int, t);
}
__device__ __forceinline__ float sel4(float a0, float a1, float a2, float a3, int q) {
    float x = (q & 1) ? a1 : a0;
    float y = (q & 1) ? a3 : a2;
    return (q & 2) ? y : x;
}

// ---------------------------------------------------------------------------
// W conversion -> frag-order Wg [384 rows][256 k] fp16: 24 row-tiles x 8
// k-tiles = 192 tiles x 512 halfs. Rows 0-63 Wq (x log2e), 64-127 Wk, rest Wv.
// Thread = (tile, lane): reads 8 fp32, writes its 16B frag chunk contiguously.
// ---------------------------------------------------------------------------
__global__ __launch_bounds__(256, 1) void wcvt_kernel(
    const float* __restrict__ Wq, const float* __restrict__ Wk,
    const float* __restrict__ Wv, unsigned short* __restrict__ Wg)
{
    int tid = blockIdx.x * 256 + threadIdx.x;       // 0..12287
    int tile = tid >> 6, lane = tid & 63;
    int r = (tile >> 3) * 16 + (lane & 15);
    int c = (tile & 7) * 32 + (lane >> 4) * 8;
    const float* src; float sc;
    if (r < 64)       { src = Wq + r * CCH + c;        sc = L2E; }
    else if (r < 128) { src = Wk + (r - 64) * CCH + c; sc = 1.0f; }
    else              { src = Wv + (r - 128) * CCH + c; sc = 1.0f; }
    float4 a = *reinterpret_cast<const float4*>(src);
    float4 b4 = *reinterpret_cast<const float4*>(src + 4);
    uint4 out;
    out.x = pk2h(a.x * sc, a.y * sc);
    out.y = pk2h(a.z * sc, a.w * sc);
    out.z = pk2h(b4.x * sc, b4.y * sc);
    out.w = pk2h(b4.z * sc, b4.w * sc);
    *reinterpret_cast<uint4*>(Wg + tile * 512 + lane * 8) = out;
}

// ---------------------------------------------------------------------------
// fp16 MFMA projection v11: frag-order W loads (contiguous 1KB/wave) and
// frag-order Q/K/V stores (one 8B store/lane, contiguous 512B/wave).
// Compute identical to v9 (bit-identical results).
// ---------------------------------------------------------------------------
__global__ __launch_bounds__(256, 2) void proj_kernel(
    const float* __restrict__ x1, const float* __restrict__ x2,
    const unsigned short* __restrict__ Wg,
    const float* __restrict__ bq, const float* __restrict__ bk,
    const float* __restrict__ bv,
    unsigned short* __restrict__ Qf, unsigned short* __restrict__ Kf,
    unsigned short* __restrict__ Vt)
{
    __shared__ unsigned short xs[32][XSTR];

    const int Lb = blockIdx.x;
    const int sb = Lb & 7;              // XCD-locality swizzle
    const int tile = Lb >> 3;
    const int s = sb >> 2, b = sb & 3;
    const float* x = s ? x2 : x1;
    const int n0 = tile * 32;
    const int t = threadIdx.x;
    const int lane = t & 63;
    const int w = __builtin_amdgcn_readfirstlane(t >> 6);
    const int quad = lane >> 4, lq = lane & 15;

    // stage x^T fp16 into LDS
    {
        const int n = t & 31;
        const int g = t >> 5;
        const float* xb = x + (size_t)(b * CCH) * NPIX + n0;
        #pragma unroll
        for (int i = 0; i < 8; ++i) {
            int c0 = g * 4 + i * 32;
            u16x4 hv;
            #pragma unroll
            for (int j = 0; j < 4; ++j)
                hv[j] = f2h(xb[(size_t)(c0 + j) * NPIX + n]);
            *reinterpret_cast<u16x4*>(&xs[n][c0]) = hv;
        }
    }
    __syncthreads();

    // hoist x fragments (both ntiles, full K=256)
    h16x8 xf[2][8];
    #pragma unroll
    for (int nt = 0; nt < 2; ++nt)
        #pragma unroll
        for (int ks = 0; ks < 8; ++ks)
            xf[nt][ks] = lds_fragh(&xs[nt * 16 + lq][ks * 32 + quad * 8]);

    unsigned short* Qb = Qf + (size_t)(s * BAT + b) * (NPIX * HID);
    unsigned short* Kb = Kf + (size_t)(s * BAT + b) * (NPIX * HID);
    unsigned short* Vb = Vt + (size_t)(s * BAT + b) * ((size_t)CCH * NPIX);

    // W fragment double-buffer, frag-order contiguous loads
    h16x8 wf[2][8];
    {
        const unsigned short* wp = Wg + (size_t)(w * 6 * 8) * 512 + lane * 8;
        #pragma unroll
        for (int ks = 0; ks < 8; ++ks) wf[0][ks] = ldg_fragh(wp + ks * 512);
    }

    #pragma unroll
    for (int hloop = 0; hloop < 6; ++hloop) {
        const int cur = hloop & 1;
        const int idx = w * 6 + hloop;                  // wave-uniform, 0..23
        const int kind = idx < 4 ? 0 : (idx < 8 ? 1 : 2);

        if (hloop < 5) {
            const unsigned short* wp = Wg + (size_t)((idx + 1) * 8) * 512 + lane * 8;
            #pragma unroll
            for (int ks = 0; ks < 8; ++ks) wf[cur ^ 1][ks] = ldg_fragh(wp + ks * 512);
        }

        if (kind == 2) {
            // V: D[n][c] = mfma(xf, wf): m = n0+nt*16+quad*4+reg, c = cbase+lq
            const int cbase = (idx - 8) * 16;
            const float bbv = bv[cbase + lq];
            #pragma unroll
            for (int nt = 0; nt < 2; ++nt) {
                f32x4 acc = (f32x4){0.f, 0.f, 0.f, 0.f};
                #pragma unroll
                for (int ks = 0; ks < 8; ++ks)
                    acc = __builtin_amdgcn_mfma_f32_16x16x32_f16(xf[nt][ks], wf[cur][ks], acc, 0, 0, 0);
                u16x4 pk;
                #pragma unroll
                for (int reg = 0; reg < 4; ++reg) pk[reg] = f2h(acc[reg] + bbv);
                size_t off = (size_t)((idx - 8) * 128 + (n0 >> 5)) * 512
                           + (nt * 2 + (quad >> 1)) * 128 + lq * 8 + (quad & 1) * 4;
                *reinterpret_cast<unsigned long long*>(Vb + off) =
                    __builtin_bit_cast(unsigned long long, pk);
            }
        } else {
            // Q/K: D[h][n] = mfma(wf, xf): h = hb16*16+quad*4+reg, n = n0+nt*16+lq
            unsigned short* dq = (kind ? Kb : Qb);
            const float* bias = (kind ? bk : bq);
            const float scl = kind ? 1.0f : L2E;
            const int hb16 = kind ? (idx - 4) : idx;     // 0..3
            float bb4[4];
            #pragma unroll
            for (int reg = 0; reg < 4; ++reg)
                bb4[reg] = bias[hb16 * 16 + quad * 4 + reg] * scl;
            #pragma unroll
            for (int nt = 0; nt < 2; ++nt) {
                f32x4 acc = (f32x4){0.f, 0.f, 0.f, 0.f};
                #pragma unroll
                for (int ks = 0; ks < 8; ++ks)
                    acc = __builtin_amdgcn_mfma_f32_16x16x32_f16(wf[cur][ks], xf[nt][ks], acc, 0, 0, 0);
                u16x4 pk;
                #pragma unroll
                for (int reg = 0; reg < 4; ++reg) pk[reg] = f2h(acc[reg] + bb4[reg]);
                size_t off = (size_t)((n0 >> 4) + nt) * 1024 + (hb16 >> 1) * 512
                           + ((hb16 & 1) * 2 + (quad >> 1)) * 128 + lq * 8 + (quad & 1) * 4;
                *reinterpret_cast<unsigned long long*>(dq + off) =
                    __builtin_bit_cast(unsigned long long, pk);
            }
        }
    }
}

// ---------------------------------------------------------------------------
// Score-max kernel (v8 structure, frag-order contiguous loads).
// ---------------------------------------------------------------------------
__global__ __launch_bounds__(256, 2) void smax_kernel(
    const unsigned short* __restrict__ Qf, const unsigned short* __restrict__ Kf,
    float* __restrict__ Mg)
{
    __shared__ float Msh[4][64];

    const int Lb = blockIdx.x;
    const int g = Lb & 7;
    const int ntile = Lb >> 3;
    const int d = g >> 2, b = g & 3;
    const int db = d * BAT + b;
    const int s = d, r = 1 - d;
    const int n0 = ntile * 64;

    const int t = threadIdx.x;
    const int lane = t & 63;
    const int w = __builtin_amdgcn_readfirstlane(t >> 6);
    const int quad = lane >> 4, lq = lane & 15;

    const unsigned short* Qb = Qf + (size_t)(s * BAT + b) * (NPIX * HID);
    const unsigned short* Kb = Kf + (size_t)(r * BAT + b) * (NPIX * HID);

    h16x8 qf[4][2];
    #pragma unroll
    for (int nt = 0; nt < 4; ++nt)
        #pragma unroll
        for (int ks = 0; ks < 2; ++ks)
            qf[nt][ks] = ldg_fragh(Qb + (size_t)((((n0 >> 4) + nt) * 2) + ks) * 512 + lane * 8);

    float mx[4] = {-3.0e38f, -3.0e38f, -3.0e38f, -3.0e38f};

    h16x8 kfA[2][2], kfB[2][2];

#define SMAX_LOAD(BUF, IT)                                                      \
    {                                                                           \
        _Pragma("unroll")                                                       \
        for (int mt = 0; mt < 2; ++mt) {                                        \
            _Pragma("unroll")                                                   \
            for (int ks = 0; ks < 2; ++ks)                                      \
                BUF[mt][ks] = ldg_fragh(                                        \
                    Kb + (size_t)(((IT) * 8 + w * 2 + mt) * 2 + ks) * 512       \
                       + lane * 8);                                             \
        }                                                                       \
    }
#define SMAX_STEP(BUF)                                                          \
    {                                                                           \
        f32x4 Sacc[2][4];                                                       \
        _Pragma("unroll")                                                       \
        for (int mt = 0; mt < 2; ++mt) {                                        \
            _Pragma("unroll")                                                   \
            for (int nt = 0; nt < 4; ++nt)                                      \
                Sacc[mt][nt] = (f32x4){0.f, 0.f, 0.f, 0.f};                     \
        }                                                                       \
        _Pragma("unroll")                                                       \
        for (int mt = 0; mt < 2; ++mt) {                                        \
            _Pragma("unroll")                                                   \
            for (int ks = 0; ks < 2; ++ks) {                                    \
                _Pragma("unroll")                                               \
                for (int nt = 0; nt < 4; ++nt)                                  \
                    Sacc[mt][nt] = __builtin_amdgcn_mfma_f32_16x16x32_f16(      \
                        BUF[mt][ks], qf[nt][ks], Sacc[mt][nt], 0, 0, 0);        \
            }                                                                   \
        }                                                                       \
        _Pragma("unroll")                                                       \
        for (int mt = 0; mt < 2; ++mt) {                                        \
            _Pragma("unroll")                                                   \
            for (int nt = 0; nt < 4; ++nt)                                      \
                mx[nt] = fmaxf(mx[nt],                                          \
                    fmaxf(fmaxf(Sacc[mt][nt][0], Sacc[mt][nt][1]),              \
                          fmaxf(Sacc[mt][nt][2], Sacc[mt][nt][3])));            \
        }                                                                       \
    }

    SMAX_LOAD(kfA, 0)
    for (int it = 0; it < 32; it += 2) {
        if (it + 1 < 32) SMAX_LOAD(kfB, it + 1)
        SMAX_STEP(kfA)
        if (it + 2 < 32) SMAX_LOAD(kfA, it + 2)
        SMAX_STEP(kfB)
    }
#undef SMAX_LOAD
#undef SMAX_STEP

    #pragma unroll
    for (int nt = 0; nt < 4; ++nt) {
        mx[nt] = fmaxf(mx[nt], __shfl_xor(mx[nt], 16));
        mx[nt] = fmaxf(mx[nt], __shfl_xor(mx[nt], 32));
    }
    Msh[w][quad * 16 + lq] = sel4(mx[0], mx[1], mx[2], mx[3], quad);
    __syncthreads();

    if (t < 64) {
        float m = fmaxf(fmaxf(Msh[0][t], Msh[1][t]), fmaxf(Msh[2][t], Msh[3][t]));
        Mg[(size_t)db * NPIX + n0 + t] = m;
    }
}

// ---------------------------------------------------------------------------
// Flash cross-attention v11 = v9 structure with frag-order contiguous loads.
// Precomputed-max softmax, one barrier per 128-m iter, V registers preloaded.
// ---------------------------------------------------------------------------
__global__ __launch_bounds__(256, 2) void attn_kernel(
    const float* __restrict__ x1, const float* __restrict__ x2,
    const unsigned short* __restrict__ Qf, const unsigned short* __restrict__ Kf,
    const unsigned short* __restrict__ Vt,
    const float* __restrict__ Mg, const float* __restrict__ gamma,
    float* __restrict__ out)
{
    __shared__ unsigned short PT[2][64 * PTS];   // P^T [n=64][m=128], fp16, dbuf
    __shared__ float Lsh[4][64];

    const int Lb = blockIdx.x;
    const int g = Lb & 7;                        // XCD-locality swizzle
    const int ntile = Lb >> 3;
    const int d = g >> 2, b = g & 3;
    const int db = d * BAT + b;
    const int s = d, r = 1 - d;
    const int n0 = ntile * 64;

    const int t = threadIdx.x;
    const int lane = t & 63;
    const int w = __builtin_amdgcn_readfirstlane(t >> 6);
    const int quad = lane >> 4, lq = lane & 15;

    const unsigned short* Qb = Qf + (size_t)(s * BAT + b) * (NPIX * HID);
    const unsigned short* Kb = Kf + (size_t)(r * BAT + b) * (NPIX * HID);
    const unsigned short* Vb = Vt + (size_t)(r * BAT + b) * ((size_t)CCH * NPIX);

    // per-column max (exp2 units) from smax_kernel; column n = ... + lq
    float Mn[4];
    #pragma unroll
    for (int nt = 0; nt < 4; ++nt)
        Mn[nt] = Mg[(size_t)db * NPIX + n0 + nt * 16 + lq];

    // Q fragments, persistent (B-frags), contiguous loads
    h16x8 qf[4][2];
    #pragma unroll
    for (int nt = 0; nt < 4; ++nt)
        #pragma unroll
        for (int ks = 0; ks < 2; ++ks)
            qf[nt][ks] = ldg_fragh(Qb + (size_t)((((n0 >> 4) + nt) * 2) + ks) * 512 + lane * 8);

    f32x4 Oacc[4][4];
    #pragma unroll
    for (int rt = 0; rt < 4; ++rt)
        #pragma unroll
        for (int ct = 0; ct < 4; ++ct)
            Oacc[rt][ct] = (f32x4){0.f, 0.f, 0.f, 0.f};

    float Li[4] = {0.f, 0.f, 0.f, 0.f};

    // K(0) and V(0) fragments (contiguous 1KB/wave loads)
    h16x8 kf[2][2];
    #pragma unroll
    for (int mt = 0; mt < 2; ++mt)
        #pragma unroll
        for (int ks = 0; ks < 2; ++ks)
            kf[mt][ks] = ldg_fragh(Kb + (size_t)((w * 2 + mt) * 2 + ks) * 512 + lane * 8);

    h16x8 vf[4][4];   // vf[ks][rt]
    #pragma unroll
    for (int ks = 0; ks < 4; ++ks)
        #pragma unroll
        for (int rt = 0; rt < 4; ++rt)
            vf[ks][rt] = ldg_fragh(Vb + (size_t)((w * 4 + rt) * 128 + ks) * 512 + lane * 8);

    for (int it = 0; it < 32; ++it) {
        const int buf = it & 1;

        // ---- S phase: Sacc init to -Mn (col n = lq for all 4 C regs) ----
        f32x4 Sacc[2][4];
        #pragma unroll
        for (int mt = 0; mt < 2; ++mt)
            #pragma unroll
            for (int nt = 0; nt < 4; ++nt)
                Sacc[mt][nt] = (f32x4){-Mn[nt], -Mn[nt], -Mn[nt], -Mn[nt]};
        #pragma unroll
        for (int mt = 0; mt < 2; ++mt)
            #pragma unroll
            for (int ks = 0; ks < 2; ++ks)
                #pragma unroll
                for (int nt = 0; nt < 4; ++nt)
                    Sacc[mt][nt] = __builtin_amdgcn_mfma_f32_16x16x32_f16(
                        kf[mt][ks], qf[nt][ks], Sacc[mt][nt], 0, 0, 0);

        // issue K(it+1): exp2 covers its latency pre-barrier
        const int itk = (it < 31) ? it + 1 : 31;
        #pragma unroll
        for (int mt = 0; mt < 2; ++mt)
            #pragma unroll
            for (int ks = 0; ks < 2; ++ks)
                kf[mt][ks] = ldg_fragh(Kb + (size_t)((itk * 8 + w * 2 + mt) * 2 + ks) * 512
                                          + lane * 8);

        // ---- softmax: P = exp2(S - M) <= 1, fp16, straight to LDS ----
        #pragma unroll
        for (int mt = 0; mt < 2; ++mt)
            #pragma unroll
            for (int nt = 0; nt < 4; ++nt) {
                float p0 = __builtin_amdgcn_exp2f(Sacc[mt][nt][0]);
                float p1 = __builtin_amdgcn_exp2f(Sacc[mt][nt][1]);
                float p2 = __builtin_amdgcn_exp2f(Sacc[mt][nt][2]);
                float p3 = __builtin_amdgcn_exp2f(Sacc[mt][nt][3]);
                Li[nt] += (p0 + p1) + (p2 + p3);
                uint2 pk2;
                pk2.x = pk2h(p0, p1);
                pk2.y = pk2h(p2, p3);
                *reinterpret_cast<uint2*>(
                    &PT[buf][(nt * 16 + lq) * PTS + w * 32 + mt * 16 + quad * 4]) = pk2;
            }
        __syncthreads();   // the ONLY barrier; K loads complete by now

        // ---- PV: pure register+LDS MFMA over 128 m ----
        #pragma unroll
        for (int ks = 0; ks < 4; ++ks) {
            h16x8 pf[4];
            #pragma unroll
            for (int ct = 0; ct < 4; ++ct)
                pf[ct] = lds_fragh(&PT[buf][(ct * 16 + lq) * PTS + ks * 32 + quad * 8]);
            #pragma unroll
            for (int rt = 0; rt < 4; ++rt)
                #pragma unroll
                for (int ct = 0; ct < 4; ++ct)
                    Oacc[rt][ct] = __builtin_amdgcn_mfma_f32_16x16x32_f16(
                        vf[ks][rt], pf[ct], Oacc[rt][ct], 0, 0, 0);
        }

        // issue V(it+1): S(it+1)+exp2 covers latency
        const int itv = (it < 31) ? it + 1 : 31;
        #pragma unroll
        for (int ks = 0; ks < 4; ++ks)
            #pragma unroll
            for (int rt = 0; rt < 4; ++rt)
                vf[ks][rt] = ldg_fragh(Vb + (size_t)((w * 4 + rt) * 128 + itv * 4 + ks) * 512
                                          + lane * 8);
    }

    // ---- epilogue: merge per-wave/per-quad L, then out = xq + g*O/L ----
    #pragma unroll
    for (int nt = 0; nt < 4; ++nt) {
        Li[nt] += __shfl_xor(Li[nt], 16);
        Li[nt] += __shfl_xor(Li[nt], 32);
    }
    Lsh[w][quad * 16 + lq] = sel4(Li[0], Li[1], Li[2], Li[3], quad);
    __syncthreads();

    float inv[4];
    #pragma unroll
    for (int nt = 0; nt < 4; ++nt) {
        int i = nt * 16 + lq;
        inv[nt] = 1.0f / ((Lsh[0][i] + Lsh[1][i]) + (Lsh[2][i] + Lsh[3][i]));
    }

    const float* xq = d ? x2 : x1;
    const float gm = gamma[0];

    #pragma unroll
    for (int rt = 0; rt < 4; ++rt)
        #pragma unroll
        for (int ct = 0; ct < 4; ++ct)
            #pragma unroll
            for (int rg = 0; rg < 4; ++rg) {
                int c = w * 64 + rt * 16 + quad * 4 + rg;
                int nn = n0 + ct * 16 + lq;
                size_t src = (size_t)(b * CCH + c) * NPIX + nn;
                size_t dst = (size_t)(db * CCH + c) * NPIX + nn;
                out[dst] = xq[src] + gm * Oacc[rt][ct][rg] * inv[ct];
            }
}

// ---------------------------------------------------------------------------
extern "C" void kernel_launch(void* const* d_in, const int* in_sizes, int n_in,
                              void* d_out, int out_size, void* d_ws, size_t ws_size,
                              hipStream_t stream) {
    (void)in_sizes; (void)n_in; (void)out_size; (void)ws_size;
    const float* x1 = (const float*)d_in[0];
    const float* x2 = (const float*)d_in[1];
    const float* Wq = (const float*)d_in[2];
    const float* bq = (const float*)d_in[3];
    const float* Wk = (const float*)d_in[4];
    const float* bk = (const float*)d_in[5];
    const float* Wv = (const float*)d_in[6];
    const float* bv = (const float*)d_in[7];
    const float* gm = (const float*)d_in[8];
    float* out = (float*)d_out;

    // ws (u16 elems): Qf 2.1M | Kf 2.1M | Vt 8.4M | Wg 98304, then Mg fp32 32768
    unsigned short* ws = (unsigned short*)d_ws;
    unsigned short* Qf = ws;
    unsigned short* Kf = Qf + (size_t)2097152;
    unsigned short* Vt = Kf + (size_t)2097152;
    unsigned short* Wg = Vt + (size_t)8388608;
    float* Mg = (float*)(Wg + 98304);

    wcvt_kernel<<<dim3(48), dim3(256), 0, stream>>>(Wq, Wk, Wv, Wg);
    proj_kernel<<<dim3(1024), dim3(256), 0, stream>>>(
        x1, x2, Wg, bq, bk, bv, Qf, Kf, Vt);
    smax_kernel<<<dim3(512), dim3(256), 0, stream>>>(Qf, Kf, Mg);
    attn_kernel<<<dim3(512), dim3(256), 0, stream>>>(
        x1, x2, Qf, Kf, Vt, Mg, gm, out);
}